// Round 3
// baseline (13.982 us; speedup 1.0000x reference)
//
#include <hip/hip_runtime.h>
#include <math.h>

typedef _Float16 f16;
typedef _Float16 f16x2 __attribute__((ext_vector_type(2)));

constexpr int   DATA_DIM  = 28;
constexpr int   MAX_STEPS = 16;
constexpr float STEP_SIZE = 0.001f;
constexpr float BG        = 1.0f;
constexpr int   CELLS     = 8;     // N^3
constexpr int   NVOX      = 64;    // 4^3 leaf-resolution voxels
constexpr int   VOX_H     = 28;    // halves per voxel record (56 B)

__device__ __forceinline__ float fdot2(unsigned w, f16x2 s, float acc) {
#if __has_builtin(__builtin_amdgcn_fdot2)
    return __builtin_amdgcn_fdot2(__builtin_bit_cast(f16x2, w), s, acc, false);
#else
    f16x2 a = __builtin_bit_cast(f16x2, w);
    return acc + (float)a.x * (float)s.x + (float)a.y * (float)s.y;
#endif
}

// Geometry for one step: from ray parameter TC produce voxel index LIDX and
// step length DTV. Pure VALU + one 64-bit mask shift — no LDS on this chain.
#define GEOM(TC, LIDX, DTV)                                                  \
  {                                                                          \
    float px = fmaf((TC), dnx, otx);                                         \
    float py = fmaf((TC), dny, oty);                                         \
    float pz = fmaf((TC), dnz, otz);                                         \
    float pcx = fminf(fmaxf(px, 0.0f), 0.999999f);                           \
    float pcy = fminf(fmaxf(py, 0.0f), 0.999999f);                           \
    float pcz = fminf(fmaxf(pz, 0.0f), 0.999999f);                           \
    int vx = (int)(pcx * 4.0f);                                              \
    int vy = (int)(pcy * 4.0f);                                              \
    int vz = (int)(pcz * 4.0f);                                              \
    (LIDX) = (vx << 4) | (vy << 2) | vz;                                     \
    bool d2 = (d2mask >> (LIDX)) & 1ull;                                     \
    float invlen = d2 ? 4.0f : 2.0f;                                         \
    float lenv   = d2 ? 0.25f : 0.5f;                                        \
    int   shf    = d2 ? 0 : 1;                                               \
    float cfx = (float)(vx >> shf);                                          \
    float cfy = (float)(vy >> shf);                                          \
    float cfz = (float)(vz >> shf);                                          \
    float plx = fmaf(px, invlen, -cfx);                                      \
    float ply = fmaf(py, invlen, -cfy);                                      \
    float plz = fmaf(pz, invlen, -cfz);                                      \
    float t1x = -plx * ivx, t2x = t1x + ivx;                                 \
    float t1y = -ply * ivy, t2y = t1y + ivy;                                 \
    float t1z = -plz * ivz, t2z = t1z + ivz;                                 \
    float mn = fmaxf(fmaxf(fminf(t1x,t2x), fminf(t1y,t2y)), fminf(t1z,t2z)); \
    float mx = fminf(fminf(fmaxf(t1x,t2x), fmaxf(t1y,t2y)), fmaxf(t1z,t2z)); \
    float smin = fmaxf(mn, 0.0f);                                            \
    float smax = fminf(mx, 1000000000.0f);                                   \
    (DTV) = fmaf(smax - smin, lenv, STEP_SIZE);                              \
  }

#define PREF(LI, Q0,Q1,Q2,Q3,Q4,Q5,Q6)                                       \
  {                                                                          \
    const uint2* _r = (const uint2*)(s_vh + (LI) * VOX_H);                   \
    Q0=_r[0]; Q1=_r[1]; Q2=_r[2]; Q3=_r[3]; Q4=_r[4]; Q5=_r[5]; Q6=_r[6];   \
  }

// One pipelined step: break if wave inactive; advance geometry for s+1 and
// issue its record loads; shade step s from the already-loaded QA registers.
#define STEP(QA0,QA1,QA2,QA3,QA4,QA5,QA6, QB0,QB1,QB2,QB3,QB4,QB5,QB6)      \
  {                                                                          \
    bool act = t_cur < tmax;                                                 \
    if (!__any(act)) break;                                                  \
    float t_next = act ? t_cur + dtc : t_cur;                                \
    int lin; float dtn;                                                      \
    GEOM(t_next, lin, dtn);                                                  \
    PREF(lin, QB0,QB1,QB2,QB3,QB4,QB5,QB6);                                  \
    unsigned D0=QA0.x, D1=QA0.y, D2=QA1.x, D3=QA1.y, D4=QA2.x, D5=QA2.y,     \
             D6=QA3.x, D7=QA3.y, D8=QA4.x, D9=QA4.y, D10=QA5.x, D11=QA5.y,   \
             D12=QA6.x, D13=QA6.y;                                           \
    float a0=0.f, a1=0.f, a2=0.f;                                            \
    a0=fdot2(D0,shA0,a0); a0=fdot2(D1,shA1,a0); a0=fdot2(D2,shA2,a0);        \
    a0=fdot2(D3,shA3,a0); a0=fdot2(D4,shA4,a0);                              \
    a1=fdot2(D4,shB0,a1); a1=fdot2(D5,shB1,a1); a1=fdot2(D6,shB2,a1);        \
    a1=fdot2(D7,shB3,a1); a1=fdot2(D8,shB4,a1);                              \
    a2=fdot2(D9,shA0,a2); a2=fdot2(D10,shA1,a2); a2=fdot2(D11,shA2,a2);      \
    a2=fdot2(D12,shA3,a2); a2=fdot2(D13,shA4,a2);                            \
    f16x2 lastp = __builtin_bit_cast(f16x2, D13);                            \
    float sigma = fmaxf((float)lastp.y, 0.0f);                               \
    float att = __expf(katt * dtc * sigma);                                  \
    float weight = light * (1.0f - att);                                     \
    float w = act ? weight : 0.0f;                                           \
    float r0 = __builtin_amdgcn_rcpf(1.0f + __expf(-a0));                    \
    float r1 = __builtin_amdgcn_rcpf(1.0f + __expf(-a1));                    \
    float r2 = __builtin_amdgcn_rcpf(1.0f + __expf(-a2));                    \
    o0 = fmaf(w, r0, o0);                                                    \
    o1 = fmaf(w, r1, o1);                                                    \
    o2 = fmaf(w, r2, o2);                                                    \
    light = act ? light * att : light;                                       \
    t_cur = t_next;                                                          \
    dtc = dtn;                                                               \
  }

__global__ __launch_bounds__(256) void vr_kernel(
    const float* __restrict__ origins,
    const float* __restrict__ dirs,
    const float* __restrict__ viewdirs,
    const float* __restrict__ data,
    const int*   __restrict__ child,
    const float* __restrict__ offset,
    const float* __restrict__ invradius_p,
    float* __restrict__ out,
    int B)
{
    __shared__ f16 s_vh[NVOX * VOX_H];   // fp16 voxel records, stride 56 B
    __shared__ int s_fent[NVOX];

    const int t0   = threadIdx.x;
    const int lane = t0 & 63;

    // Wave-uniform 64-bit mask: bit v = 1 if voxel v resolves at depth 2.
    unsigned long long d2mask;
    {
        int vx = lane >> 4, vy = (lane >> 2) & 3, vz = lane & 3;
        int e0 = ((vx >> 1) << 2) | ((vy >> 1) << 1) | (vz >> 1);
        int ch = child[e0];
        d2mask = __ballot(ch != 0);
    }

    if (t0 < NVOX) {
        int vx = t0 >> 4, vy = (t0 >> 2) & 3, vz = t0 & 3;
        int e0 = ((vx >> 1) << 2) | ((vy >> 1) << 1) | (vz >> 1);
        int ch = child[e0];
        int fe = (ch != 0) ? ch * CELLS + (((vx & 1) << 2) | ((vy & 1) << 1) | (vz & 1))
                           : e0;
        s_fent[t0] = fe;
    }
    __syncthreads();
    for (int i = t0; i < NVOX * VOX_H; i += 256) {
        int v = i / VOX_H, j = i - v * VOX_H;
        s_vh[i] = (f16)data[s_fent[v] * DATA_DIM + j];
    }
    __syncthreads();

    int tid = blockIdx.x * 256 + t0;
    if (tid >= B) return;

    float ox = origins[tid*3+0], oy = origins[tid*3+1], oz = origins[tid*3+2];
    float dx = dirs[tid*3+0],    dy = dirs[tid*3+1],    dz = dirs[tid*3+2];
    float vdx = viewdirs[tid*3+0], vdy = viewdirs[tid*3+1], vdz = viewdirs[tid*3+2];
    float invr = invradius_p[0];
    float otx = offset[0] + ox * invr;
    float oty = offset[1] + oy * invr;
    float otz = offset[2] + oz * invr;

    // SH-9 basis, fp16-packed in two alignments (even/odd start).
    float sh[9];
    {
        const float C0 = 0.28209479177387814f;
        const float C1 = 0.4886025119029199f;
        sh[0] = C0;
        sh[1] = -C1 * vdy;
        sh[2] =  C1 * vdz;
        sh[3] = -C1 * vdx;
        sh[4] =  1.0925484305920792f * vdx * vdy;
        sh[5] = -1.0925484305920792f * vdy * vdz;
        sh[6] =  0.31539156525252005f * (2.0f*vdz*vdz - vdx*vdx - vdy*vdy);
        sh[7] = -1.0925484305920792f * vdx * vdz;
        sh[8] =  0.5462742152960396f * (vdx*vdx - vdy*vdy);
    }
    f16x2 shA0 = f16x2{(f16)sh[0], (f16)sh[1]};
    f16x2 shA1 = f16x2{(f16)sh[2], (f16)sh[3]};
    f16x2 shA2 = f16x2{(f16)sh[4], (f16)sh[5]};
    f16x2 shA3 = f16x2{(f16)sh[6], (f16)sh[7]};
    f16x2 shA4 = f16x2{(f16)sh[8], (f16)0.0f};
    f16x2 shB0 = f16x2{(f16)0.0f,  (f16)sh[0]};
    f16x2 shB1 = f16x2{(f16)sh[1], (f16)sh[2]};
    f16x2 shB2 = f16x2{(f16)sh[3], (f16)sh[4]};
    f16x2 shB3 = f16x2{(f16)sh[5], (f16)sh[6]};
    f16x2 shB4 = f16x2{(f16)sh[7], (f16)sh[8]};

    float nrm = sqrtf(dx*dx + dy*dy + dz*dz);
    float dnx = dx / nrm, dny = dy / nrm, dnz = dz / nrm;
    float ivx = 1.0f / (dnx + 1e-9f);
    float ivy = 1.0f / (dny + 1e-9f);
    float ivz = 1.0f / (dnz + 1e-9f);

    float t_cur, tmax;
    {
        float t1x = -otx * ivx, t2x = t1x + ivx;
        float t1y = -oty * ivy, t2y = t1y + ivy;
        float t1z = -otz * ivz, t2z = t1z + ivz;
        float mn = fmaxf(fmaxf(fminf(t1x,t2x), fminf(t1y,t2y)), fminf(t1z,t2z));
        float mx = fminf(fminf(fmaxf(t1x,t2x), fmaxf(t1y,t2y)), fmaxf(t1z,t2z));
        t_cur = fmaxf(mn, 0.0f);
        tmax  = fminf(mx, 1000000000.0f);
    }

    const float katt = -(1.0f / invr);
    float light = 1.0f;
    float o0 = 0.0f, o1 = 0.0f, o2 = 0.0f;

    uint2 A0,A1,A2,A3,A4,A5,A6, B0,B1,B2,B3,B4,B5,B6;
    int li0; float dtc;
    GEOM(t_cur, li0, dtc);
    PREF(li0, A0,A1,A2,A3,A4,A5,A6);

    #pragma unroll
    for (int s = 0; s < MAX_STEPS; s += 2) {
        STEP(A0,A1,A2,A3,A4,A5,A6, B0,B1,B2,B3,B4,B5,B6);
        STEP(B0,B1,B2,B3,B4,B5,B6, A0,A1,A2,A3,A4,A5,A6);
    }

    out[tid*3+0] = fmaf(light, BG, o0);
    out[tid*3+1] = fmaf(light, BG, o1);
    out[tid*3+2] = fmaf(light, BG, o2);
}

extern "C" void kernel_launch(void* const* d_in, const int* in_sizes, int n_in,
                              void* d_out, int out_size, void* d_ws, size_t ws_size,
                              hipStream_t stream) {
    const float* origins  = (const float*)d_in[0];
    const float* dirs     = (const float*)d_in[1];
    const float* viewdirs = (const float*)d_in[2];
    const float* data     = (const float*)d_in[3];
    const int*   child    = (const int*)d_in[4];
    const float* offset   = (const float*)d_in[5];
    const float* invrad   = (const float*)d_in[6];
    float* out = (float*)d_out;
    int B = in_sizes[0] / 3;
    int block = 256;
    int grid = (B + block - 1) / block;
    vr_kernel<<<grid, block, 0, stream>>>(origins, dirs, viewdirs, data, child,
                                          offset, invrad, out, B);
}